// Round 5
// baseline (679.595 us; speedup 1.0000x reference)
//
#include <hip/hip_runtime.h>
#include <cmath>

// TensorTrainGaussian: v <- (softmax_b(W_m) * NormalPDF(x_m)) @ v, M=32 steps of
// 16x16, N=131072. Compute-bound (1.07e9 exp2).
//
// Lessons: r1 (scalar, global tables) 244us — uniform table reads stayed VMEM,
//   ~26 busy-cyc/elem. r2/r3 (v2f tables) regressed — {s,s} broadcasts
//   materialize as v_movs. r4 (2 samples/lane packed) 224us — instr count halved
//   but 1 wave/SIMD exposed latency (VALUBusy 46%).
// r5: tables in LDS, read via uniform-address ds_read_b128 (broadcast,
//   conflict-free). Values land in VGPRs -> inner element is ALL-VGPR:
//   s = fma(P, x^2, fma(Q, x, R)); e = exp2(s); acc = fmac(va, e).
//   4 VALU + 1 exp per element, zero movs. 1 sample/lane -> 2048 waves
//   (2/SIMD) for TLP. LDS: PQ[512] + R[8192] floats = 34 KB.
// Early exit (provable): columns of softmax(W) sum to 1, pdf <= 0.798 =>
//   sum(v) shrinks by >= x0.798/step, so once sum(v) < 5e-17 the final
//   log(lik+eps) is within log(1+5e-17/2.22e-16)=0.20 of the reference (tol .72).

#define TT_N 131072
#define TT_M 32

typedef float v4f __attribute__((ext_vector_type(4)));

// ws layout (floats): z[16] | PQ[16][16][2] | R[32][16][16]
#define WS_Z  0
#define WS_PQ 16
#define WS_R  (16 + 512)
#define TBL_FLOATS (512 + 8192)

__global__ __launch_bounds__(512) void tt_prep(const float* __restrict__ Wk0,
                                               const float* __restrict__ W,
                                               const float* __restrict__ mu,
                                               const float* __restrict__ sigma,
                                               float* __restrict__ ws) {
    const int t = threadIdx.x;
    const float LOG2E = 1.4426950408889634f;
    float* z  = ws + WS_Z;
    float* PQ = ws + WS_PQ;
    float* RT = ws + WS_R;

    if (t < 16) {
        float mx = -1e30f;
        for (int i = 0; i < 16; ++i) mx = fmaxf(mx, Wk0[i]);
        float se = 0.f;
        for (int i = 0; i < 16; ++i) se += __expf(Wk0[i] - mx);
        z[t] = __expf(Wk0[t] - mx) / se;
    }

    if (t < 256) {
        const int a = t >> 4, b = t & 15;     // transposed [a][b]
        float s  = sigma[b * 16 + a];
        float mm = mu[b * 16 + a];
        float c2 = 0.72134752044448f / (s * s);   // 0.5*log2(e)/sigma^2
        PQ[(a * 16 + b) * 2]     = -c2;           // P
        PQ[(a * 16 + b) * 2 + 1] = 2.0f * c2 * mm;  // Q
    }

    // one thread per (m, a): column softmax over b of W[m, b, a]
    const int m = t >> 4;
    const int a = t & 15;
    const float* Wc = W + m * 256 + a;  // stride 16 over b
    float mx = -1e30f;
    #pragma unroll
    for (int b = 0; b < 16; ++b) mx = fmaxf(mx, Wc[b * 16]);
    float se = 0.f;
    #pragma unroll
    for (int b = 0; b < 16; ++b) se += __expf(Wc[b * 16] - mx);
    float lse = __log2f(se);
    #pragma unroll
    for (int b = 0; b < 16; ++b) {
        float s     = sigma[b * 16 + a];
        float mm    = mu[b * 16 + a];
        float inv_s = 1.0f / s;
        float c2    = 0.72134752044448f / (s * s);
        float lw    = (Wc[b * 16] - mx) * LOG2E - lse;   // log2 softmax weight
        RT[m * 256 + a * 16 + b] =
            lw + __log2f(inv_s * 0.3989422804014327f) - c2 * mm * mm;
    }
}

__global__ __launch_bounds__(256) void tt_main(const float* __restrict__ X,
                                               const float* __restrict__ ws,
                                               float* __restrict__ out) {
    __shared__ float lds[TBL_FLOATS];   // PQ[512] | R[8192]

    // stage tables global -> LDS, coalesced float4
    {
        const v4f* src = (const v4f*)(ws + WS_PQ);
        v4f* dst = (v4f*)lds;
        for (int i = threadIdx.x; i < TBL_FLOATS / 4; i += 256) dst[i] = src[i];
    }
    __syncthreads();

    const float* ldsPQ = lds;         // [a][b][{P,Q}]
    const float* ldsR  = lds + 512;   // [m][a][b]

    const int n = blockIdx.x * 256 + threadIdx.x;
    const float* zp = ws + WS_Z;

    float v[16], acc[16];
    #pragma unroll
    for (int a = 0; a < 16; ++a) v[a] = zp[a];

    const float* xp = X + (size_t)n * TT_M;
    float S = 0.f;

    #pragma unroll 1
    for (int mg = 0; mg < 8; ++mg) {
        v4f x4 = *(const v4f*)(xp + mg * 4);
        #pragma unroll
        for (int ms = 0; ms < 4; ++ms) {
            const float xm = (ms == 0) ? x4.x : (ms == 1) ? x4.y : (ms == 2) ? x4.z : x4.w;
            const float x2 = xm * xm;
            const float* Rm = ldsR + (mg * 4 + ms) * 256;

            #pragma unroll
            for (int b = 0; b < 16; ++b) acc[b] = 0.f;

            #pragma unroll
            for (int a = 0; a < 16; ++a) {
                const float va = v[a];
                const v4f* pq4 = (const v4f*)(ldsPQ + a * 32);
                const v4f* r4  = (const v4f*)(Rm + a * 16);
                #pragma unroll
                for (int g = 0; g < 4; ++g) {
                    v4f pq0 = pq4[g * 2];       // P0 Q0 P1 Q1
                    v4f pq1 = pq4[g * 2 + 1];   // P2 Q2 P3 Q3
                    v4f rr  = r4[g];
                    float s0 = __fmaf_rn(pq0.x, x2, __fmaf_rn(pq0.y, xm, rr.x));
                    float s1 = __fmaf_rn(pq0.z, x2, __fmaf_rn(pq0.w, xm, rr.y));
                    float s2 = __fmaf_rn(pq1.x, x2, __fmaf_rn(pq1.y, xm, rr.z));
                    float s3 = __fmaf_rn(pq1.z, x2, __fmaf_rn(pq1.w, xm, rr.w));
                    acc[g * 4 + 0] = __fmaf_rn(va, __builtin_amdgcn_exp2f(s0), acc[g * 4 + 0]);
                    acc[g * 4 + 1] = __fmaf_rn(va, __builtin_amdgcn_exp2f(s1), acc[g * 4 + 1]);
                    acc[g * 4 + 2] = __fmaf_rn(va, __builtin_amdgcn_exp2f(s2), acc[g * 4 + 2]);
                    acc[g * 4 + 3] = __fmaf_rn(va, __builtin_amdgcn_exp2f(s3), acc[g * 4 + 3]);
                }
            }

            float s0 = (acc[0] + acc[1]) + (acc[2] + acc[3]);
            float s1 = (acc[4] + acc[5]) + (acc[6] + acc[7]);
            float s2 = (acc[8] + acc[9]) + (acc[10] + acc[11]);
            float s3 = (acc[12] + acc[13]) + (acc[14] + acc[15]);
            S = (s0 + s1) + (s2 + s3);
            #pragma unroll
            for (int b = 0; b < 16; ++b) v[b] = acc[b];

            if (__all(S < 5e-17f)) { mg = 8; break; }
        }
    }

    out[n] = logf(S + 2.2204460492503131e-16f);
}

extern "C" void kernel_launch(void* const* d_in, const int* in_sizes, int n_in,
                              void* d_out, int out_size, void* d_ws, size_t ws_size,
                              hipStream_t stream) {
    const float* X     = (const float*)d_in[0];
    const float* Wk0   = (const float*)d_in[1];
    const float* W     = (const float*)d_in[2];
    const float* mu    = (const float*)d_in[3];
    const float* sigma = (const float*)d_in[4];
    float* out = (float*)d_out;
    float* ws  = (float*)d_ws;

    tt_prep<<<1, 512, 0, stream>>>(Wk0, W, mu, sigma, ws);
    tt_main<<<TT_N / 256, 256, 0, stream>>>(X, ws, out);
}

// Round 7
// 100.731 us; speedup vs baseline: 6.7466x; 6.7466x over previous
//
#include <hip/hip_runtime.h>
#include <cmath>

// TensorTrainGaussian: v <- (softmax_b(W_m) * NormalPDF(x_m)) @ v, M=32 steps of
// 16x16, N=131072. Trans-pipe-bound: 1.07e9 v_exp_f32 (8 cyc/wave64) => ~55us
// floor, ~30us with early exit.
//
// r7 design (lessons r1-r6):
//  - Pack over ADJACENT b (not samples, not tables): P/Q/R v2f pairs come
//    naturally even-aligned from LDS ds_read_b128 -> plain
//    __builtin_elementwise_fma emits v_pk_fma_f32 with zero movs / zero asm.
//    Only x (2 dups/step) and va (16 dups/step) need broadcasting - negligible.
//  - 1 sample/lane -> 2048 waves = 2/SIMD (r4: 1/SIMD exposed latency).
//  - Tables in LDS (uniform-address broadcast reads, conflict-free);
//    P/Q base laundered per step to block LICM (r5: 256-VGPR spill).
//  - Early exit (provable): columns of softmax(W) sum to 1, pdf <= 0.798 =>
//    sum(v) shrinks >= x0.798/step; once sum(v) < 5e-17 final log(lik+eps)
//    is within 0.21 of the reference floor (tolerance 0.72).

#define TT_N 131072
#define TT_M 32

typedef float v2f __attribute__((ext_vector_type(2)));
typedef float v4f __attribute__((ext_vector_type(4)));

// ws layout (floats): z[16] | P[256] | Q[256] | R[32*256], tables [a*16+b]
#define WS_Z 0
#define WS_P 16
#define WS_Q (16 + 256)
#define WS_R (16 + 512)
#define TBL_FLOATS (512 + 8192)

__global__ __launch_bounds__(512) void tt_prep(const float* __restrict__ Wk0,
                                               const float* __restrict__ W,
                                               const float* __restrict__ mu,
                                               const float* __restrict__ sigma,
                                               float* __restrict__ ws) {
    const int t = threadIdx.x;
    const float LOG2E = 1.4426950408889634f;
    float* z  = ws + WS_Z;
    float* PP = ws + WS_P;
    float* QQ = ws + WS_Q;
    float* RT = ws + WS_R;

    if (t < 16) {
        float mx = -1e30f;
        for (int i = 0; i < 16; ++i) mx = fmaxf(mx, Wk0[i]);
        float se = 0.f;
        for (int i = 0; i < 16; ++i) se += __expf(Wk0[i] - mx);
        z[t] = __expf(Wk0[t] - mx) / se;
    }

    if (t < 256) {
        const int a = t >> 4, b = t & 15;     // transposed [a][b]
        float s  = sigma[b * 16 + a];
        float mm = mu[b * 16 + a];
        float c2 = 0.72134752044448f / (s * s);   // 0.5*log2(e)/sigma^2
        PP[a * 16 + b] = -c2;
        QQ[a * 16 + b] = 2.0f * c2 * mm;
    }

    // one thread per (m, a): column softmax over b of W[m, b, a]
    const int m = t >> 4;
    const int a = t & 15;
    const float* Wc = W + m * 256 + a;  // stride 16 over b
    float mx = -1e30f;
    #pragma unroll
    for (int b = 0; b < 16; ++b) mx = fmaxf(mx, Wc[b * 16]);
    float se = 0.f;
    #pragma unroll
    for (int b = 0; b < 16; ++b) se += __expf(Wc[b * 16] - mx);
    float lse = __log2f(se);
    #pragma unroll
    for (int b = 0; b < 16; ++b) {
        float s     = sigma[b * 16 + a];
        float mm    = mu[b * 16 + a];
        float inv_s = 1.0f / s;
        float c2    = 0.72134752044448f / (s * s);
        float lw    = (Wc[b * 16] - mx) * LOG2E - lse;   // log2 softmax weight
        RT[m * 256 + a * 16 + b] =
            lw + __log2f(inv_s * 0.3989422804014327f) - c2 * mm * mm;
    }
}

__global__ __launch_bounds__(256) void tt_main(const float* __restrict__ X,
                                               const float* __restrict__ ws,
                                               float* __restrict__ out) {
    __shared__ float lds[TBL_FLOATS];   // P[256] | Q[256] | R[8192]
    {
        const v4f* src = (const v4f*)(ws + WS_P);
        v4f* dst = (v4f*)lds;
        for (int i = threadIdx.x; i < TBL_FLOATS / 4; i += 256) dst[i] = src[i];
    }
    __syncthreads();

    const int n = blockIdx.x * 256 + threadIdx.x;
    const float* zp = ws + WS_Z;

    v2f v[8], acc[8];
    #pragma unroll
    for (int p = 0; p < 8; ++p) v[p] = (v2f){zp[2 * p], zp[2 * p + 1]};

    const float* xp = X + (size_t)n * TT_M;
    float S = 1.f;
    float xn = xp[0];

    #pragma unroll 1
    for (int m = 0; m < TT_M; ++m) {
        const float xm = xn;
        xn = xp[(m + 1 < TT_M) ? m + 1 : m];   // prefetch next x under compute
        const float xq = xm * xm;
        const v2f xx  = {xm, xm};
        const v2f xx2 = {xq, xq};

        int lo = 0;
        asm volatile("" : "+v"(lo));   // launder: block LICM of P/Q loads
        const float* Pm = lds + lo;            // P[a*16+b]
        const float* Qm = lds + 256 + lo;      // Q
        const float* Rm = lds + 512 + m * 256; // R (m-varying)

        #pragma unroll
        for (int p = 0; p < 8; ++p) acc[p] = (v2f){0.f, 0.f};

        #pragma unroll
        for (int a = 0; a < 16; ++a) {
            const float vas = (a & 1) ? v[a >> 1].y : v[a >> 1].x;
            const v2f va2 = {vas, vas};
            #pragma unroll
            for (int h = 0; h < 4; ++h) {
                v4f P4 = *(const v4f*)(Pm + a * 16 + h * 4);
                v4f Q4 = *(const v4f*)(Qm + a * 16 + h * 4);
                v4f R4 = *(const v4f*)(Rm + a * 16 + h * 4);
                v2f t0 = __builtin_elementwise_fma(Q4.xy, xx, R4.xy);
                v2f s0 = __builtin_elementwise_fma(P4.xy, xx2, t0);
                v2f t1 = __builtin_elementwise_fma(Q4.zw, xx, R4.zw);
                v2f s1 = __builtin_elementwise_fma(P4.zw, xx2, t1);
                v2f e0, e1;
                e0.x = __builtin_amdgcn_exp2f(s0.x);
                e0.y = __builtin_amdgcn_exp2f(s0.y);
                e1.x = __builtin_amdgcn_exp2f(s1.x);
                e1.y = __builtin_amdgcn_exp2f(s1.y);
                acc[h * 2]     = __builtin_elementwise_fma(va2, e0, acc[h * 2]);
                acc[h * 2 + 1] = __builtin_elementwise_fma(va2, e1, acc[h * 2 + 1]);
            }
        }

        #pragma unroll
        for (int p = 0; p < 8; ++p) v[p] = acc[p];
        v2f u0 = (acc[0] + acc[1]) + (acc[2] + acc[3]);
        v2f u1 = (acc[4] + acc[5]) + (acc[6] + acc[7]);
        v2f u  = u0 + u1;
        S = u.x + u.y;
        if (__all(S < 5e-17f)) break;
    }

    out[n] = logf(S + 2.2204460492503131e-16f);
}

extern "C" void kernel_launch(void* const* d_in, const int* in_sizes, int n_in,
                              void* d_out, int out_size, void* d_ws, size_t ws_size,
                              hipStream_t stream) {
    const float* X     = (const float*)d_in[0];
    const float* Wk0   = (const float*)d_in[1];
    const float* W     = (const float*)d_in[2];
    const float* mu    = (const float*)d_in[3];
    const float* sigma = (const float*)d_in[4];
    float* out = (float*)d_out;
    float* ws  = (float*)d_ws;

    tt_prep<<<1, 512, 0, stream>>>(Wk0, W, mu, sigma, ws);
    tt_main<<<TT_N / 256, 256, 0, stream>>>(X, ws, out);
}

// Round 8
// 100.585 us; speedup vs baseline: 6.7564x; 1.0015x over previous
//
#include <hip/hip_runtime.h>
#include <cmath>

// TensorTrainGaussian: v <- (softmax_b(W_m) * NormalPDF(x_m)) @ v, M=32 steps of
// 16x16, N=131072. Trans-pipe-bound: 1.07e9 v_exp_f32 (8 cyc/wave64) => 54.6us
// floor. r7 (101us): b-packed v2f + LDS tables, but only 2 waves/SIMD (grid-
// limited) -> both pipes ~55% idle-riddled.
//
// r8: split b 4-ways across lanes (lane group g owns b in [4g,4g+4)) ->
//   524288 threads = 8192 waves = 8/SIMD, 4 blocks/CU at 34KB LDS = 32
//   waves/CU (full). Per wave-step: 96 pk_fma + 64 exp + 48 uniform b128.
//   Full v rebuilt per step with a 2-round __shfl_xor butterfly (xor1, xor2).
//   Keep LICM launder (r5: spill), exact v_exp_f32.
// Early exit (provable): softmax columns sum to 1, pdf <= 0.798 => sum(v)
//   shrinks >= x0.798/step; once sum(v) < 5e-17 final log(lik+eps) is within
//   0.21 of the reference floor (tolerance 0.72). Finer now: 16 samples/wave.

#define TT_N 131072
#define TT_M 32

typedef float v2f __attribute__((ext_vector_type(2)));
typedef float v4f __attribute__((ext_vector_type(4)));

// ws layout (floats): z[16] | P[256] | Q[256] | R[32*256], tables [a*16+b]
#define WS_Z 0
#define WS_P 16
#define WS_Q (16 + 256)
#define WS_R (16 + 512)
#define TBL_FLOATS (512 + 8192)

__global__ __launch_bounds__(512) void tt_prep(const float* __restrict__ Wk0,
                                               const float* __restrict__ W,
                                               const float* __restrict__ mu,
                                               const float* __restrict__ sigma,
                                               float* __restrict__ ws) {
    const int t = threadIdx.x;
    const float LOG2E = 1.4426950408889634f;
    float* z  = ws + WS_Z;
    float* PP = ws + WS_P;
    float* QQ = ws + WS_Q;
    float* RT = ws + WS_R;

    if (t < 16) {
        float mx = -1e30f;
        for (int i = 0; i < 16; ++i) mx = fmaxf(mx, Wk0[i]);
        float se = 0.f;
        for (int i = 0; i < 16; ++i) se += __expf(Wk0[i] - mx);
        z[t] = __expf(Wk0[t] - mx) / se;
    }

    if (t < 256) {
        const int a = t >> 4, b = t & 15;     // transposed [a][b]
        float s  = sigma[b * 16 + a];
        float mm = mu[b * 16 + a];
        float c2 = 0.72134752044448f / (s * s);   // 0.5*log2(e)/sigma^2
        PP[a * 16 + b] = -c2;
        QQ[a * 16 + b] = 2.0f * c2 * mm;
    }

    // one thread per (m, a): column softmax over b of W[m, b, a]
    const int m = t >> 4;
    const int a = t & 15;
    const float* Wc = W + m * 256 + a;  // stride 16 over b
    float mx = -1e30f;
    #pragma unroll
    for (int b = 0; b < 16; ++b) mx = fmaxf(mx, Wc[b * 16]);
    float se = 0.f;
    #pragma unroll
    for (int b = 0; b < 16; ++b) se += __expf(Wc[b * 16] - mx);
    float lse = __log2f(se);
    #pragma unroll
    for (int b = 0; b < 16; ++b) {
        float s     = sigma[b * 16 + a];
        float mm    = mu[b * 16 + a];
        float inv_s = 1.0f / s;
        float c2    = 0.72134752044448f / (s * s);
        float lw    = (Wc[b * 16] - mx) * LOG2E - lse;   // log2 softmax weight
        RT[m * 256 + a * 16 + b] =
            lw + __log2f(inv_s * 0.3989422804014327f) - c2 * mm * mm;
    }
}

static __device__ __forceinline__ v2f shfl_xor_v2f(v2f x, int mask) {
    v2f r;
    r.x = __shfl_xor(x.x, mask, 64);
    r.y = __shfl_xor(x.y, mask, 64);
    return r;
}

__global__ __launch_bounds__(512) void tt_main(const float* __restrict__ X,
                                               const float* __restrict__ ws,
                                               float* __restrict__ out) {
    __shared__ float lds[TBL_FLOATS];   // P[256] | Q[256] | R[8192]
    {
        const v4f* src = (const v4f*)(ws + WS_P);
        v4f* dst = (v4f*)lds;
        for (int i = threadIdx.x; i < TBL_FLOATS / 4; i += 512) dst[i] = src[i];
    }
    __syncthreads();

    const int tid  = blockIdx.x * 512 + threadIdx.x;
    const int n    = tid >> 2;          // 4 lanes per sample
    const int g    = tid & 3;           // b-group: b in [4g, 4g+4)
    const int boff = g << 2;

    const float* zp = ws + WS_Z;
    v2f v[8];                            // full v over b: v[p] = {v2p, v2p+1}
    #pragma unroll
    for (int p = 0; p < 8; ++p) v[p] = (v2f){zp[2 * p], zp[2 * p + 1]};

    const float* xp = X + (size_t)n * TT_M;
    float S = 1.f;
    float xn = xp[0];

    #pragma unroll 1
    for (int m = 0; m < TT_M; ++m) {
        const float xm = xn;
        xn = xp[(m + 1 < TT_M) ? m + 1 : m];
        const float xq = xm * xm;
        const v2f xx  = {xm, xm};
        const v2f xx2 = {xq, xq};

        int lo = 0;
        asm volatile("" : "+v"(lo));     // launder: block LICM of table loads
        const float* Pm = lds + lo;
        const float* Qm = lds + 256 + lo;
        const float* Rm = lds + 512 + m * 256;

        v2f a0, a1;                      // acc for local {4g,4g+1},{4g+2,4g+3}

        #pragma unroll
        for (int a = 0; a < 16; ++a) {
            const float vas = (a & 1) ? v[a >> 1].y : v[a >> 1].x;
            const v2f va2 = {vas, vas};
            const int base = a * 16 + boff;
            v4f P4 = *(const v4f*)(Pm + base);
            v4f Q4 = *(const v4f*)(Qm + base);
            v4f R4 = *(const v4f*)(Rm + base);
            v2f t0 = __builtin_elementwise_fma(Q4.xy, xx, R4.xy);
            v2f s0 = __builtin_elementwise_fma(P4.xy, xx2, t0);
            v2f t1 = __builtin_elementwise_fma(Q4.zw, xx, R4.zw);
            v2f s1 = __builtin_elementwise_fma(P4.zw, xx2, t1);
            v2f e0, e1;
            e0.x = __builtin_amdgcn_exp2f(s0.x);
            e0.y = __builtin_amdgcn_exp2f(s0.y);
            e1.x = __builtin_amdgcn_exp2f(s1.x);
            e1.y = __builtin_amdgcn_exp2f(s1.y);
            if (a == 0) { a0 = va2 * e0; a1 = va2 * e1; }
            else {
                a0 = __builtin_elementwise_fma(va2, e0, a0);
                a1 = __builtin_elementwise_fma(va2, e1, a1);
            }
        }

        // butterfly gather: rebuild full v[8] from 4 lanes' local acc pairs
        const bool hi1 = (g & 1) != 0;
        const bool hi2 = (g & 2) != 0;
        v2f r0 = shfl_xor_v2f(a0, 1), r1 = shfl_xor_v2f(a1, 1);
        v2f u0 = hi1 ? r0 : a0;
        v2f u1 = hi1 ? r1 : a1;
        v2f u2 = hi1 ? a0 : r0;
        v2f u3 = hi1 ? a1 : r1;
        v2f w0 = shfl_xor_v2f(u0, 2), w1 = shfl_xor_v2f(u1, 2);
        v2f w2 = shfl_xor_v2f(u2, 2), w3 = shfl_xor_v2f(u3, 2);
        v[0] = hi2 ? w0 : u0;  v[1] = hi2 ? w1 : u1;
        v[2] = hi2 ? w2 : u2;  v[3] = hi2 ? w3 : u3;
        v[4] = hi2 ? u0 : w0;  v[5] = hi2 ? u1 : w1;
        v[6] = hi2 ? u2 : w2;  v[7] = hi2 ? u3 : w3;

        v2f q0 = (v[0] + v[1]) + (v[2] + v[3]);
        v2f q1 = (v[4] + v[5]) + (v[6] + v[7]);
        v2f q  = q0 + q1;
        S = q.x + q.y;
        if (__all(S < 5e-17f)) break;
    }

    if (g == 0) out[n] = logf(S + 2.2204460492503131e-16f);
}

extern "C" void kernel_launch(void* const* d_in, const int* in_sizes, int n_in,
                              void* d_out, int out_size, void* d_ws, size_t ws_size,
                              hipStream_t stream) {
    const float* X     = (const float*)d_in[0];
    const float* Wk0   = (const float*)d_in[1];
    const float* W     = (const float*)d_in[2];
    const float* mu    = (const float*)d_in[3];
    const float* sigma = (const float*)d_in[4];
    float* out = (float*)d_out;
    float* ws  = (float*)d_ws;

    tt_prep<<<1, 512, 0, stream>>>(Wk0, W, mu, sigma, ws);
    tt_main<<<(TT_N * 4) / 512, 512, 0, stream>>>(X, ws, out);
}

// Round 9
// 99.276 us; speedup vs baseline: 6.8455x; 1.0132x over previous
//
#include <hip/hip_runtime.h>
#include <cmath>

// TensorTrainGaussian: v <- (softmax_b(W_m) * NormalPDF(x_m)) @ v, M=32 steps of
// 16x16, N=131072. r7/r8 counter math proved v_exp_f32 occupies the VALU issue
// stream ~8 cyc/wave (64% of all issue cycles) -> exp-issue-bound at ~100us.
//
// r9: Schraudolph exp2 folded into the tables. Prescale P'=2^23*P, Q'=2^23*Q,
//   R'=2^23*(R+127-c), c=log2(E_f[(1+f)2^-f])=0.05758 (mean-one centering:
//   per-eval multiplicative error in [-3.9%,+2.0%], zero arithmetic mean, so
//   step errors random-walk: ~0.1 in log space over 32 steps, tol 0.72).
//   Then e = as_float((int)max(s',0)): 1 pk_max/2 evals + 1 cvt_i32/eval
//   replaces each 8-cyc exp. Clamp handles underflow (negative s' -> garbage).
//   Same 2 pk_fma produce s' (tables pre-scaled). ~26 cyc/a-iter vs 44.
// Structure from r8: 4-way b-split across lanes, 8 waves/SIMD, LDS tables,
//   LICM launder, 2-round shfl_xor butterfly, provable early exit
//   (sum(v) shrinks >=x0.798/step; <5e-17 -> within 0.21+small of ref floor).

#define TT_N 131072
#define TT_M 32

typedef float v2f __attribute__((ext_vector_type(2)));
typedef float v4f __attribute__((ext_vector_type(4)));

// ws layout (floats): z[16] | P'[256] | Q'[256] | R'[32*256], tables [a*16+b]
#define WS_Z 0
#define WS_P 16
#define WS_Q (16 + 256)
#define WS_R (16 + 512)
#define TBL_FLOATS (512 + 8192)

__global__ __launch_bounds__(512) void tt_prep(const float* __restrict__ Wk0,
                                               const float* __restrict__ W,
                                               const float* __restrict__ mu,
                                               const float* __restrict__ sigma,
                                               float* __restrict__ ws) {
    const int t = threadIdx.x;
    const float LOG2E = 1.4426950408889634f;
    const float SCALE = 8388608.0f;               // 2^23
    const float BIAS  = 126.94242f;               // 127 - 0.0575812 (mean-one c)
    float* z  = ws + WS_Z;
    float* PP = ws + WS_P;
    float* QQ = ws + WS_Q;
    float* RT = ws + WS_R;

    if (t < 16) {
        float mx = -1e30f;
        for (int i = 0; i < 16; ++i) mx = fmaxf(mx, Wk0[i]);
        float se = 0.f;
        for (int i = 0; i < 16; ++i) se += __expf(Wk0[i] - mx);
        z[t] = __expf(Wk0[t] - mx) / se;
    }

    if (t < 256) {
        const int a = t >> 4, b = t & 15;     // transposed [a][b]
        float s  = sigma[b * 16 + a];
        float mm = mu[b * 16 + a];
        float c2 = 0.72134752044448f / (s * s);   // 0.5*log2(e)/sigma^2
        PP[a * 16 + b] = -c2 * SCALE;
        QQ[a * 16 + b] = 2.0f * c2 * mm * SCALE;
    }

    // one thread per (m, a): column softmax over b of W[m, b, a]
    const int m = t >> 4;
    const int a = t & 15;
    const float* Wc = W + m * 256 + a;  // stride 16 over b
    float mx = -1e30f;
    #pragma unroll
    for (int b = 0; b < 16; ++b) mx = fmaxf(mx, Wc[b * 16]);
    float se = 0.f;
    #pragma unroll
    for (int b = 0; b < 16; ++b) se += __expf(Wc[b * 16] - mx);
    float lse = __log2f(se);
    #pragma unroll
    for (int b = 0; b < 16; ++b) {
        float s     = sigma[b * 16 + a];
        float mm    = mu[b * 16 + a];
        float inv_s = 1.0f / s;
        float c2    = 0.72134752044448f / (s * s);
        float lw    = (Wc[b * 16] - mx) * LOG2E - lse;   // log2 softmax weight
        float R = lw + __log2f(inv_s * 0.3989422804014327f) - c2 * mm * mm;
        RT[m * 256 + a * 16 + b] = (R + BIAS) * SCALE;
    }
}

static __device__ __forceinline__ v2f shfl_xor_v2f(v2f x, int mask) {
    v2f r;
    r.x = __shfl_xor(x.x, mask, 64);
    r.y = __shfl_xor(x.y, mask, 64);
    return r;
}

static __device__ __forceinline__ v2f fast_exp2_pair(v2f s) {
    // s is prescaled: s = 2^23*(log2(val)+126.94); clamp to >=0, truncate, bitcast
    s = __builtin_elementwise_max(s, (v2f){0.f, 0.f});
    v2f e;
    e.x = __int_as_float((int)s.x);
    e.y = __int_as_float((int)s.y);
    return e;
}

__global__ __launch_bounds__(512) void tt_main(const float* __restrict__ X,
                                               const float* __restrict__ ws,
                                               float* __restrict__ out) {
    __shared__ float lds[TBL_FLOATS];   // P'[256] | Q'[256] | R'[8192]
    {
        const v4f* src = (const v4f*)(ws + WS_P);
        v4f* dst = (v4f*)lds;
        for (int i = threadIdx.x; i < TBL_FLOATS / 4; i += 512) dst[i] = src[i];
    }
    __syncthreads();

    const int tid  = blockIdx.x * 512 + threadIdx.x;
    const int n    = tid >> 2;          // 4 lanes per sample
    const int g    = tid & 3;           // b-group: b in [4g, 4g+4)
    const int boff = g << 2;

    const float* zp = ws + WS_Z;
    v2f v[8];                            // full v over b: v[p] = {v2p, v2p+1}
    #pragma unroll
    for (int p = 0; p < 8; ++p) v[p] = (v2f){zp[2 * p], zp[2 * p + 1]};

    const float* xp = X + (size_t)n * TT_M;
    float S = 1.f;
    float xn = xp[0];

    #pragma unroll 1
    for (int m = 0; m < TT_M; ++m) {
        const float xm = xn;
        xn = xp[(m + 1 < TT_M) ? m + 1 : m];
        const float xq = xm * xm;
        const v2f xx  = {xm, xm};
        const v2f xx2 = {xq, xq};

        int lo = 0;
        asm volatile("" : "+v"(lo));     // launder: block LICM of table loads
        const float* Pm = lds + lo;
        const float* Qm = lds + 256 + lo;
        const float* Rm = lds + 512 + m * 256;

        v2f a0, a1;                      // acc for local {4g,4g+1},{4g+2,4g+3}

        #pragma unroll
        for (int a = 0; a < 16; ++a) {
            const float vas = (a & 1) ? v[a >> 1].y : v[a >> 1].x;
            const v2f va2 = {vas, vas};
            const int base = a * 16 + boff;
            v4f P4 = *(const v4f*)(Pm + base);
            v4f Q4 = *(const v4f*)(Qm + base);
            v4f R4 = *(const v4f*)(Rm + base);
            v2f t0 = __builtin_elementwise_fma(Q4.xy, xx, R4.xy);
            v2f s0 = __builtin_elementwise_fma(P4.xy, xx2, t0);
            v2f t1 = __builtin_elementwise_fma(Q4.zw, xx, R4.zw);
            v2f s1 = __builtin_elementwise_fma(P4.zw, xx2, t1);
            v2f e0 = fast_exp2_pair(s0);
            v2f e1 = fast_exp2_pair(s1);
            if (a == 0) { a0 = va2 * e0; a1 = va2 * e1; }
            else {
                a0 = __builtin_elementwise_fma(va2, e0, a0);
                a1 = __builtin_elementwise_fma(va2, e1, a1);
            }
        }

        // butterfly gather: rebuild full v[8] from 4 lanes' local acc pairs
        const bool hi1 = (g & 1) != 0;
        const bool hi2 = (g & 2) != 0;
        v2f r0 = shfl_xor_v2f(a0, 1), r1 = shfl_xor_v2f(a1, 1);
        v2f u0 = hi1 ? r0 : a0;
        v2f u1 = hi1 ? r1 : a1;
        v2f u2 = hi1 ? a0 : r0;
        v2f u3 = hi1 ? a1 : r1;
        v2f w0 = shfl_xor_v2f(u0, 2), w1 = shfl_xor_v2f(u1, 2);
        v2f w2 = shfl_xor_v2f(u2, 2), w3 = shfl_xor_v2f(u3, 2);
        v[0] = hi2 ? w0 : u0;  v[1] = hi2 ? w1 : u1;
        v[2] = hi2 ? w2 : u2;  v[3] = hi2 ? w3 : u3;
        v[4] = hi2 ? u0 : w0;  v[5] = hi2 ? u1 : w1;
        v[6] = hi2 ? u2 : w2;  v[7] = hi2 ? u3 : w3;

        v2f q0 = (v[0] + v[1]) + (v[2] + v[3]);
        v2f q1 = (v[4] + v[5]) + (v[6] + v[7]);
        v2f q  = q0 + q1;
        S = q.x + q.y;
        if (__all(S < 5e-17f)) break;
    }

    if (g == 0) out[n] = logf(S + 2.2204460492503131e-16f);
}

extern "C" void kernel_launch(void* const* d_in, const int* in_sizes, int n_in,
                              void* d_out, int out_size, void* d_ws, size_t ws_size,
                              hipStream_t stream) {
    const float* X     = (const float*)d_in[0];
    const float* Wk0   = (const float*)d_in[1];
    const float* W     = (const float*)d_in[2];
    const float* mu    = (const float*)d_in[3];
    const float* sigma = (const float*)d_in[4];
    float* out = (float*)d_out;
    float* ws  = (float*)d_ws;

    tt_prep<<<1, 512, 0, stream>>>(Wk0, W, mu, sigma, ws);
    tt_main<<<(TT_N * 4) / 512, 512, 0, stream>>>(X, ws, out);
}